// Round 1
// baseline (854.275 us; speedup 1.0000x reference)
//
#include <hip/hip_runtime.h>

// RetinaNet head via bf16 MFMA implicit-GEMM (16x16x32) — R2 structure.
// Activations: padded NHWC bf16 [plane][(H+2)(W+2)][256], zero borders.
// Block: 64co x 256px (16x16 tile), 4 waves; wave = 64co x 64px as 4x4 tiles.
// R2: DOUBLE-BUFFERED LDS pipeline (T3 minimum 2-phase). Per ci-chunk(32):
// stage of chunk ch+1 is issued BEFORE the MFMA compute of chunk ch; the
// single __syncthreads() per chunk (implicit vmcnt(0)+barrier) lands AFTER
// 144 MFMAs of overlap, hiding the HBM/L2 staging latency that previously
// stalled the 2-barrier-per-K-step loop at ~40% MfmaUtil. LDS = 120 KB
// (1 block/CU; in-block overlap replaces cross-block overlap).
// All prep (NCHW->NHWC bf16, weight blobs, border zeros) fused in ONE dispatch.

typedef __attribute__((ext_vector_type(8))) short short8;
typedef __attribute__((ext_vector_type(4))) float floatx4;

#define LVLTOT 14143  // sum of padded (H+2)(W+2) over 5 levels

__device__ __forceinline__ unsigned short f2bf(float f) {
  unsigned int u = __float_as_uint(f);
  unsigned int r = (u + 0x7fffu + ((u >> 16) & 1u)) >> 16;
  return (unsigned short)r;
}

__device__ __forceinline__ void gload_lds16(const void* g, void* l) {
  __builtin_amdgcn_global_load_lds(
      (const __attribute__((address_space(1))) unsigned int*)g,
      (__attribute__((address_space(3))) unsigned int*)l, 16, 0, 0);
}

// ================= fused prep: xprep + wprep + border zero =================
// blocks [0,1090): xprep strips; [1090,3970): wprep (one co per block);
// [3970,4770): border zeroing (exact enumeration).
struct PrepArgs {
  const float* f[5];
  const float* w[10];
  unsigned short* wdst[10];
  int wblk_off[11];
  int cout[10];
  unsigned short* x0;
  unsigned short* bufA;
  unsigned short* bufB;
};

__global__ __launch_bounds__(256) void prep(PrepArgs A) {
  static const int Ht[5] = {100, 50, 25, 13, 7};
  static const int Wpt[5] = {102, 52, 27, 15, 9};
  static const int LOFFt[5] = {0, 10404, 13108, 13837, 14062};
  __shared__ float ts[32][33];
  const int bid = blockIdx.x;
  const int t = threadIdx.x;

  if (bid < 1090) {
    // ---- xprep: one 32-px row-strip, all 256 ch, one n ----
    int sid = bid % 545, n = bid / 545;
    int l, h, wb;
    if (sid < 400)      { l = 0; h = sid >> 2; wb = sid & 3; }
    else if (sid < 500) { l = 1; h = (sid - 400) >> 1; wb = (sid - 400) & 1; }
    else if (sid < 525) { l = 2; h = sid - 500; wb = 0; }
    else if (sid < 538) { l = 3; h = sid - 525; wb = 0; }
    else                { l = 4; h = sid - 538; wb = 0; }
    const float* f = A.f[l];
    int H = Ht[l], W = H, Wp = Wpt[l], loff = LOFFt[l];
    int w0 = wb * 32;
    for (int s = 0; s < 8; s++) {
      int ch0 = s * 32;
      __syncthreads();
#pragma unroll
      for (int r4 = 0; r4 < 4; r4++) {
        int ch = ch0 + (t >> 5) + r4 * 8;
        int px = w0 + (t & 31);
        float v = 0.f;
        if (px < W) v = f[(((size_t)n * 256 + ch) * H + h) * W + px];
        ts[(t >> 5) + r4 * 8][t & 31] = v;
      }
      __syncthreads();
      int pxl = t >> 3, c4 = t & 7;
      if (w0 + pxl < W) {
        unsigned short pk[4];
#pragma unroll
        for (int k = 0; k < 4; k++) pk[k] = f2bf(ts[c4 * 4 + k][pxl]);
        *(unsigned long long*)(A.x0 +
            ((size_t)n * LVLTOT + loff + (size_t)(h + 1) * Wp + (w0 + pxl + 1)) *
                256 + ch0 + c4 * 4) = *(unsigned long long*)pk;
      }
    }
    return;
  }

  if (bid < 3970) {
    // ---- wprep: block = one padded co of one tensor; thread = ci ----
    int b2 = bid - 1090;
    int tix = 0;
    while (b2 >= A.wblk_off[tix + 1]) tix++;
    int co = b2 - A.wblk_off[tix];
    int ci = t;
    bool valid = co < A.cout[tix];
    const float* w = A.w[tix];
    unsigned short* dst = A.wdst[tix];
    int cb = co >> 6, col = co & 63, chk = ci >> 5, qd = (ci >> 3) & 3, j = ci & 7;
#pragma unroll
    for (int tap = 0; tap < 9; tap++) {
      float v = valid ? w[((size_t)co * 256 + ci) * 9 + tap] : 0.f;
      dst[((((size_t)(cb * 8 + chk) * 9 + tap) * 4 + qd) * 64 + col) * 8 + j] =
          f2bf(v);
    }
    return;
  }

  // ---- border zero: items = 800 border px x 32 octs per plane ----
  {
    static const int BCUM[6] = {0, 404, 608, 712, 768, 800};
    int b3 = bid - 3970;             // [0,800): plane = b3/100
    int plane = b3 / 100;
    int item = (b3 % 100) * 256 + t; // [0,25600)
    int pxi = item >> 5, oct = item & 31;
    if (pxi >= 800) return;
    int l = 0;
    while (pxi >= BCUM[l + 1]) l++;
    int j = pxi - BCUM[l];
    int Wp = Wpt[l];
    int r, c;
    if (j < Wp)            { r = 0; c = j; }
    else if (j < 2 * Wp)   { r = Wp - 1; c = j - Wp; }
    else { int k = j - 2 * Wp; r = 1 + (k >> 1); c = (k & 1) ? Wp - 1 : 0; }
    size_t px = (size_t)LOFFt[l] + (size_t)r * Wp + c;
    unsigned short* base = (plane < 4)
                               ? (A.bufA + (size_t)plane * LVLTOT * 256)
                               : (A.bufB + (size_t)(plane - 4) * LVLTOT * 256);
    floatx4 z;
    z[0] = z[1] = z[2] = z[3] = 0.f;
    *(floatx4*)(base + px * 256 + oct * 8) = z;
  }
}

// ---- tile decode (71 tiles over 5 levels) ----
__device__ __forceinline__ void decode_tile(int tile, int& l, int& h0, int& w0,
                                            int& H, int& W, int& Wp, int& loff) {
  const int Ht[5] = {100, 50, 25, 13, 7};
  const int Wpt[5] = {102, 52, 27, 15, 9};
  const int TXt[5] = {7, 4, 2, 1, 1};
  const int LOFFt[5] = {0, 10404, 13108, 13837, 14062};
  int tloc;
  if (tile < 49) { l = 0; tloc = tile; }
  else if (tile < 65) { l = 1; tloc = tile - 49; }
  else if (tile < 69) { l = 2; tloc = tile - 65; }
  else if (tile < 70) { l = 3; tloc = tile - 69; }
  else { l = 4; tloc = 0; }
  H = Ht[l]; W = H; Wp = Wpt[l]; loff = LOFFt[l];
  int ty = tloc / TXt[l], tx = tloc - ty * TXt[l];
  h0 = ty * 16; w0 = tx * 16;
}

// ---- staging of one ci-chunk(32) into the given LDS buffers ----
// (needs in scope: lane, wv, xoff[6])
#define CONV_STAGE(INP, WBLOB, CB, CH, LW, LX)                                 \
  {                                                                            \
    const unsigned short* wsrc =                                               \
        (WBLOB) + ((size_t)((CB) * 8 + (CH))) * 18432;                         \
    _Pragma("unroll") for (int i = 0; i < 9; i++)                              \
      gload_lds16(wsrc + i * 2048 + wv * 512 + lane * 8,                       \
                  (LW) + i * 2048 + wv * 512);                                 \
    _Pragma("unroll") for (int g = 0; g < 6; g++)                              \
      gload_lds16((INP) + xoff[g] + (CH) * 32, (LX) + wv * 3072 + g * 512);    \
  }

// ---- compute of one ci-chunk(32) from the given LDS buffers ----
// (needs in scope: wv, q, n16, acc[4][4])
#define CONV_COMPUTE(LW, LX)                                                   \
  {                                                                            \
    const short8* xw = (const short8*)(LW);                                    \
    const short8* xx = (const short8*)(LX);                                    \
    _Pragma("unroll") for (int tdx = 0; tdx < 3; tdx++) {                      \
      short8 bfr[6];                                                           \
      _Pragma("unroll") for (int rw = 0; rw < 6; rw++)                         \
        bfr[rw] = xx[q * 384 + (wv * 4 + rw) * 18 + n16 + tdx];                \
      _Pragma("unroll") for (int tdy = 0; tdy < 3; tdy++) {                    \
        const int tap = tdy * 3 + tdx;                                         \
        _Pragma("unroll") for (int cc = 0; cc < 4; cc++) {                     \
          short8 afr = xw[(tap * 4 + q) * 64 + cc * 16 + n16];                 \
          _Pragma("unroll") for (int rr = 0; rr < 4; rr++)                     \
            acc[cc][rr] = __builtin_amdgcn_mfma_f32_16x16x32_bf16(             \
                afr, bfr[rr + tdy], acc[cc][rr], 0, 0, 0);                     \
        }                                                                      \
      }                                                                        \
    }                                                                          \
  }

// ---- double-buffered K-loop: stage(ch+1) issued BEFORE compute(ch); the
// single __syncthreads per chunk (vmcnt(0)+barrier) lands after the MFMAs,
// so staging latency overlaps compute (T3 minimum 2-phase template). ----
#define CONV_MAIN_LOOP(INP, WBLOB, CB)                                         \
  {                                                                            \
    size_t xoff[6];                                                            \
    _Pragma("unroll") for (int g = 0; g < 6; g++) {                            \
      int px = g * 64 + lane;                                                  \
      int r = px / 18, c = px - r * 18;                                        \
      int hh = h0 + r; if (hh > Hpad - 1) hh = Hpad - 1;                       \
      int ww = w0 + c; if (ww > Wp - 1) ww = Wp - 1;                           \
      xoff[g] = ((size_t)hh * Wp + ww) * 256 + wv * 8;                         \
    }                                                                          \
    CONV_STAGE(INP, WBLOB, CB, 0, lds_w[0], lds_x[0])                          \
    __syncthreads();                                                           \
    for (int cp = 0; cp < 4; cp++) {                                           \
      CONV_STAGE(INP, WBLOB, CB, 2 * cp + 1, lds_w[1], lds_x[1])               \
      CONV_COMPUTE(lds_w[0], lds_x[0])                                         \
      __syncthreads();                                                         \
      if (cp < 3) {                                                            \
        CONV_STAGE(INP, WBLOB, CB, 2 * cp + 2, lds_w[0], lds_x[0])             \
      }                                                                        \
      CONV_COMPUTE(lds_w[1], lds_x[1])                                         \
      __syncthreads();                                                         \
    }                                                                          \
  }

// ---- tower conv layer (bf16 in -> bf16 out, +bias, ReLU) ----
__global__ __launch_bounds__(256) void conv_tower_mfma(
    const unsigned short* __restrict__ xin, unsigned short* __restrict__ xout,
    const unsigned short* __restrict__ wblob_cls,
    const unsigned short* __restrict__ wblob_box,
    const float* __restrict__ bias_cls, const float* __restrict__ bias_box,
    int in_n_stride, int in_tw_stride) {
  __shared__ __align__(16) unsigned short lds_w[2][18432];
  __shared__ __align__(16) unsigned short lds_x[2][12288];
  const int t = threadIdx.x, lane = t & 63, wv = t >> 6;
  const int q = lane >> 4, n16 = lane & 15;
  int l, h0, w0, H, W, Wp, loff;
  decode_tile(blockIdx.x, l, h0, w0, H, W, Wp, loff);
  const int Hpad = H + 2;
  const int cb = blockIdx.y;
  const int n = blockIdx.z >> 1, tw = blockIdx.z & 1;
  const unsigned short* wblob = tw ? wblob_box : wblob_cls;
  const float* bias = tw ? bias_box : bias_cls;
  const unsigned short* inp =
      xin + ((size_t)n * in_n_stride + (size_t)tw * in_tw_stride + loff) * 256;
  unsigned short* outp = xout + ((size_t)(n * 2 + tw) * LVLTOT + loff) * 256;

  floatx4 acc[4][4];
#pragma unroll
  for (int i = 0; i < 4; i++)
#pragma unroll
    for (int jj = 0; jj < 4; jj++) acc[i][jj] = (floatx4){0.f, 0.f, 0.f, 0.f};

  CONV_MAIN_LOOP(inp, wblob, cb)

  // epilogue: +bias, relu, bf16, store 4 consecutive channels (8B) per lane
#pragma unroll
  for (int cc = 0; cc < 4; cc++) {
    floatx4 bb = *(const floatx4*)(bias + cb * 64 + cc * 16 + q * 4);
#pragma unroll
    for (int rr = 0; rr < 4; rr++) {
      int h = h0 + wv * 4 + rr;
      int w_ = w0 + n16;
      if (h < H && w_ < W) {
        unsigned short pk[4];
#pragma unroll
        for (int rg = 0; rg < 4; rg++)
          pk[rg] = f2bf(fmaxf(acc[cc][rr][rg] + bb[rg], 0.f));
        size_t base =
            ((size_t)(h + 1) * Wp + (w_ + 1)) * 256 + cb * 64 + cc * 16 + q * 4;
        *(unsigned long long*)(outp + base) = *(unsigned long long*)pk;
      }
    }
  }
}

// ---- merged final conv (y<12: cls cb=y; y==12: box), permuted fp32 out ----
__global__ __launch_bounds__(256) void conv_final_mfma(
    const unsigned short* __restrict__ xin, float* __restrict__ out,
    const unsigned short* __restrict__ wblob_cls,
    const unsigned short* __restrict__ wblob_box,
    const float* __restrict__ bias_cls, const float* __restrict__ bias_box) {
  __shared__ __align__(16) unsigned short lds_w[2][18432];
  __shared__ __align__(16) unsigned short lds_x[2][12288];
  const int t = threadIdx.x, lane = t & 63, wv = t >> 6;
  const int q = lane >> 4, n16 = lane & 15;
  int l, h0, w0, H, W, Wp, loff;
  decode_tile(blockIdx.x, l, h0, w0, H, W, Wp, loff);
  const int Hpad = H + 2;
  const int yb = blockIdx.y;
  const bool is_cls = yb < 12;
  const int cb = is_cls ? yb : 0;
  const int tw = is_cls ? 0 : 1;
  const int Cout = is_cls ? 720 : 36;
  const unsigned short* wblob = is_cls ? wblob_cls : wblob_box;
  const float* bias = is_cls ? bias_cls : bias_box;
  const int n = blockIdx.z;
  const int RB[5] = {0, 90000, 112500, 118125, 119646};
  const unsigned short* inp = xin + ((size_t)(n * 2 + tw) * LVLTOT + loff) * 256;

  floatx4 acc[4][4];
#pragma unroll
  for (int i = 0; i < 4; i++)
#pragma unroll
    for (int jj = 0; jj < 4; jj++) acc[i][jj] = (floatx4){0.f, 0.f, 0.f, 0.f};

  CONV_MAIN_LOOP(inp, wblob, cb)

#pragma unroll
  for (int cc = 0; cc < 4; cc++) {
    int co0 = cb * 64 + cc * 16 + q * 4;
    if (co0 >= Cout) continue;
    floatx4 bb = *(const floatx4*)(bias + co0);
    int a = is_cls ? (co0 / 80) : (co0 >> 2);
    int col0 = is_cls ? (co0 - a * 80) : 80;
#pragma unroll
    for (int rr = 0; rr < 4; rr++) {
      int h = h0 + wv * 4 + rr;
      int w_ = w0 + n16;
      if (h < H && w_ < W) {
        size_t ridx = (size_t)RB[l] + ((size_t)h * W + w_) * 9 + a;
        floatx4 v;
#pragma unroll
        for (int rg = 0; rg < 4; rg++) v[rg] = acc[cc][rr][rg] + bb[rg];
        *(floatx4*)(out + ((size_t)n * 120087 + ridx) * 84 + col0) = v;
      }
    }
  }
}

extern "C" void kernel_launch(void* const* d_in, const int* in_sizes, int n_in,
                              void* d_out, int out_size, void* d_ws,
                              size_t ws_size, hipStream_t stream) {
  // ws layout (bytes):
  //   bufB [0, 28964864)    (X0 aliased to bufB planes 2,3: dead after layer 1)
  //   X0   [14482432, 28964864)
  //   bufA [28964864, 57929728)
  //   tower blobs 8 x 1179648 at 57929728 (cls0..3, box0..3)
  //   cls final blob 3538944 at 67366912; box final blob 294912 at 70905856
  char* ws = (char*)d_ws;
  unsigned short* bufB = (unsigned short*)(ws);
  unsigned short* X0 = (unsigned short*)(ws + 14482432);
  unsigned short* bufA = (unsigned short*)(ws + 28964864);
  unsigned short* tb[8];
  for (int i = 0; i < 8; i++)
    tb[i] = (unsigned short*)(ws + 57929728 + (size_t)i * 1179648);
  unsigned short* fb_cls = (unsigned short*)(ws + 67366912);
  unsigned short* fb_box = (unsigned short*)(ws + 70905856);

  float* out = (float*)d_out;

  PrepArgs pa;
  for (int i = 0; i < 5; i++) pa.f[i] = (const float*)d_in[i];
  for (int i = 0; i < 4; i++) {
    pa.w[i] = (const float*)d_in[5 + 2 * i];       // cls_w0..3
    pa.w[4 + i] = (const float*)d_in[13 + 2 * i];  // box_w0..3
    pa.wdst[i] = tb[i];
    pa.wdst[4 + i] = tb[4 + i];
    pa.cout[i] = pa.cout[4 + i] = 256;
  }
  pa.w[8] = (const float*)d_in[21]; pa.wdst[8] = fb_cls; pa.cout[8] = 720;
  pa.w[9] = (const float*)d_in[23]; pa.wdst[9] = fb_box; pa.cout[9] = 36;
  // padded-co block counts: towers 256 each, cls 768, box 64
  int off = 0;
  for (int i = 0; i < 8; i++) { pa.wblk_off[i] = off; off += 256; }
  pa.wblk_off[8] = off; off += 768;
  pa.wblk_off[9] = off; off += 64;
  pa.wblk_off[10] = off;  // 2880
  pa.x0 = X0;
  pa.bufA = bufA;
  pa.bufB = bufB;

  prep<<<dim3(4770), 256, 0, stream>>>(pa);

  const float *cls_b[4], *box_b[4];
  for (int i = 0; i < 4; i++) {
    cls_b[i] = (const float*)d_in[6 + 2 * i];
    box_b[i] = (const float*)d_in[14 + 2 * i];
  }

  dim3 gt(71, 4, 4);
  conv_tower_mfma<<<gt, 256, 0, stream>>>(X0, bufA, tb[0], tb[4], cls_b[0],
                                          box_b[0], LVLTOT, 0);
  conv_tower_mfma<<<gt, 256, 0, stream>>>(bufA, bufB, tb[1], tb[5], cls_b[1],
                                          box_b[1], 2 * LVLTOT, LVLTOT);
  conv_tower_mfma<<<gt, 256, 0, stream>>>(bufB, bufA, tb[2], tb[6], cls_b[2],
                                          box_b[2], 2 * LVLTOT, LVLTOT);
  conv_tower_mfma<<<gt, 256, 0, stream>>>(bufA, bufB, tb[3], tb[7], cls_b[3],
                                          box_b[3], 2 * LVLTOT, LVLTOT);

  conv_final_mfma<<<dim3(71, 13, 2), 256, 0, stream>>>(
      bufB, out, fb_cls, fb_box, (const float*)d_in[22], (const float*)d_in[24]);
}

// Round 2
// 789.961 us; speedup vs baseline: 1.0814x; 1.0814x over previous
//
#include <hip/hip_runtime.h>

// RetinaNet head via bf16 MFMA implicit-GEMM — R3 structure.
// Activations: padded NHWC bf16 [plane][(H+2)(W+2)][256], zero borders.
// R3: 32x32x16 MFMA, ci-chunk=16, FULL double-buffered LDS (W+X) at
// 77824 B -> 2 blocks/CU (the R2 post-mortem: pipelining must not cost
// the 2-waves/SIMD cross-block overlap). Block: 64co x 512px (16 rows x
// 32 cols), 4 waves; wave = 64co x (4 rows x 32 cols); MFMA px-dim = one
// 32-wide row. Per chunk per wave: 18 A + 18 B ds_read_b128 feed 72 MFMA
// (64 FLOP/LDS-byte vs R1's 42.7). Stage(c+1) issued BEFORE compute(c);
// the single __syncthreads per chunk (vmcnt(0)+barrier) lands after the
// MFMAs, hiding staging latency.
// W blob layout: [cb][chunk16][tap][ct(2)][hi(2)][co32][8ci].
// X LDS layout: [hi(2)][18 rows][34 cols][8ci] (1224 units + pad to 1280).

typedef __attribute__((ext_vector_type(8))) short short8;
typedef __attribute__((ext_vector_type(4))) float floatx4;
typedef __attribute__((ext_vector_type(16))) float floatx16;

#define LVLTOT 14143  // sum of padded (H+2)(W+2) over 5 levels

__device__ __forceinline__ unsigned short f2bf(float f) {
  unsigned int u = __float_as_uint(f);
  unsigned int r = (u + 0x7fffu + ((u >> 16) & 1u)) >> 16;
  return (unsigned short)r;
}

__device__ __forceinline__ void gload_lds16(const void* g, void* l) {
  __builtin_amdgcn_global_load_lds(
      (const __attribute__((address_space(1))) unsigned int*)g,
      (__attribute__((address_space(3))) unsigned int*)l, 16, 0, 0);
}

// ================= fused prep: xprep + wprep + border zero =================
struct PrepArgs {
  const float* f[5];
  const float* w[10];
  unsigned short* wdst[10];
  int wblk_off[11];
  int cout[10];
  unsigned short* x0;
  unsigned short* bufA;
  unsigned short* bufB;
};

__global__ __launch_bounds__(256) void prep(PrepArgs A) {
  static const int Ht[5] = {100, 50, 25, 13, 7};
  static const int Wpt[5] = {102, 52, 27, 15, 9};
  static const int LOFFt[5] = {0, 10404, 13108, 13837, 14062};
  __shared__ float ts[32][33];
  const int bid = blockIdx.x;
  const int t = threadIdx.x;

  if (bid < 1090) {
    // ---- xprep: one 32-px row-strip, all 256 ch, one n ----
    int sid = bid % 545, n = bid / 545;
    int l, h, wb;
    if (sid < 400)      { l = 0; h = sid >> 2; wb = sid & 3; }
    else if (sid < 500) { l = 1; h = (sid - 400) >> 1; wb = (sid - 400) & 1; }
    else if (sid < 525) { l = 2; h = sid - 500; wb = 0; }
    else if (sid < 538) { l = 3; h = sid - 525; wb = 0; }
    else                { l = 4; h = sid - 538; wb = 0; }
    const float* f = A.f[l];
    int H = Ht[l], W = H, Wp = Wpt[l], loff = LOFFt[l];
    int w0 = wb * 32;
    for (int s = 0; s < 8; s++) {
      int ch0 = s * 32;
      __syncthreads();
#pragma unroll
      for (int r4 = 0; r4 < 4; r4++) {
        int ch = ch0 + (t >> 5) + r4 * 8;
        int px = w0 + (t & 31);
        float v = 0.f;
        if (px < W) v = f[(((size_t)n * 256 + ch) * H + h) * W + px];
        ts[(t >> 5) + r4 * 8][t & 31] = v;
      }
      __syncthreads();
      int pxl = t >> 3, c4 = t & 7;
      if (w0 + pxl < W) {
        unsigned short pk[4];
#pragma unroll
        for (int k = 0; k < 4; k++) pk[k] = f2bf(ts[c4 * 4 + k][pxl]);
        *(unsigned long long*)(A.x0 +
            ((size_t)n * LVLTOT + loff + (size_t)(h + 1) * Wp + (w0 + pxl + 1)) *
                256 + ch0 + c4 * 4) = *(unsigned long long*)pk;
      }
    }
    return;
  }

  if (bid < 3970) {
    // ---- wprep: block = one padded co of one tensor; thread = ci ----
    // New layout for 32x32x16: [cb][chunk(ci>>4)][tap][ct][hi][co32][8]
    int b2 = bid - 1090;
    int tix = 0;
    while (b2 >= A.wblk_off[tix + 1]) tix++;
    int co = b2 - A.wblk_off[tix];
    int ci = t;
    bool valid = co < A.cout[tix];
    const float* w = A.w[tix];
    unsigned short* dst = A.wdst[tix];
    int cb = co >> 6, ct = (co >> 5) & 1, co32 = co & 31;
    int chunk = ci >> 4, hi = (ci >> 3) & 1, j = ci & 7;
#pragma unroll
    for (int tap = 0; tap < 9; tap++) {
      float v = valid ? w[((size_t)co * 256 + ci) * 9 + tap] : 0.f;
      dst[((((size_t)(cb * 16 + chunk) * 9 + tap) * 2 + ct) * 2 + hi) * 256 +
          co32 * 8 + j] = f2bf(v);
    }
    return;
  }

  // ---- border zero: items = 800 border px x 32 octs per plane ----
  {
    static const int BCUM[6] = {0, 404, 608, 712, 768, 800};
    int b3 = bid - 3970;             // [0,800): plane = b3/100
    int plane = b3 / 100;
    int item = (b3 % 100) * 256 + t; // [0,25600)
    int pxi = item >> 5, oct = item & 31;
    if (pxi >= 800) return;
    int l = 0;
    while (pxi >= BCUM[l + 1]) l++;
    int j = pxi - BCUM[l];
    int Wp = Wpt[l];
    int r, c;
    if (j < Wp)            { r = 0; c = j; }
    else if (j < 2 * Wp)   { r = Wp - 1; c = j - Wp; }
    else { int k = j - 2 * Wp; r = 1 + (k >> 1); c = (k & 1) ? Wp - 1 : 0; }
    size_t px = (size_t)LOFFt[l] + (size_t)r * Wp + c;
    unsigned short* base = (plane < 4)
                               ? (A.bufA + (size_t)plane * LVLTOT * 256)
                               : (A.bufB + (size_t)(plane - 4) * LVLTOT * 256);
    floatx4 z;
    z[0] = z[1] = z[2] = z[3] = 0.f;
    *(floatx4*)(base + px * 256 + oct * 8) = z;
  }
}

// ---- tile decode (40 tiles of 16 rows x 32 cols over 5 levels) ----
__device__ __forceinline__ void decode_tile(int tile, int& l, int& h0, int& w0,
                                            int& H, int& W, int& Wp, int& loff) {
  const int Ht[5] = {100, 50, 25, 13, 7};
  const int Wpt[5] = {102, 52, 27, 15, 9};
  const int TXt[5] = {4, 2, 1, 1, 1};
  const int LOFFt[5] = {0, 10404, 13108, 13837, 14062};
  int tloc;
  if (tile < 28) { l = 0; tloc = tile; }
  else if (tile < 36) { l = 1; tloc = tile - 28; }
  else if (tile < 38) { l = 2; tloc = tile - 36; }
  else if (tile < 39) { l = 3; tloc = tile - 38; }
  else { l = 4; tloc = 0; }
  H = Ht[l]; W = H; Wp = Wpt[l]; loff = LOFFt[l];
  int ty = tloc / TXt[l], tx = tloc - ty * TXt[l];
  h0 = ty * 16; w0 = tx * 32;
}

// ---- staging of one ci-chunk(16) into the given LDS buffers ----
// W: 18 groups of 64x16B; X: 20 groups. Group g -> wave (g&3); dest is
// wave-uniform (HW adds lane*16); src per-lane. xsrc[5] precomputed.
#define CONV_STAGE(INP, WBLOB, CB, CH, LW, LX)                                 \
  {                                                                            \
    const unsigned short* wsrc =                                               \
        (WBLOB) + ((size_t)((CB) * 16 + (CH))) * 9216;                         \
    _Pragma("unroll") for (int k5 = 0; k5 < 5; k5++) {                         \
      int g = wv + 4 * k5;                                                     \
      if (g < 18) gload_lds16(wsrc + g * 512 + lane * 8, (LW) + g * 512);      \
    }                                                                          \
    _Pragma("unroll") for (int k5 = 0; k5 < 5; k5++) {                         \
      int gx = wv + 4 * k5;                                                    \
      gload_lds16((INP) + xsrc[k5] + (CH) * 16, (LX) + gx * 512);              \
    }                                                                          \
  }

// ---- compute of one ci-chunk(16): 18 A + 18 B ds_read_b128, 72 MFMA ----
// (needs: wv, hixx, wrow, col31, hi32p, acc[2][4])
#define CONV_COMPUTE(LW, LX)                                                   \
  {                                                                            \
    const short8* xw = (const short8*)(LW);                                    \
    const short8* xx = (const short8*)(LX);                                    \
    _Pragma("unroll") for (int dx = 0; dx < 3; dx++) {                         \
      short8 bfr[6];                                                           \
      _Pragma("unroll") for (int rb = 0; rb < 6; rb++)                         \
        bfr[rb] = xx[hixx + (wrow + rb) * 34 + dx + col31];                    \
      _Pragma("unroll") for (int dy = 0; dy < 3; dy++) {                       \
        const int tap = dy * 3 + dx;                                           \
        _Pragma("unroll") for (int ct = 0; ct < 2; ct++) {                     \
          short8 afr = xw[(tap * 2 + ct) * 64 + hi32p];                        \
          _Pragma("unroll") for (int pt = 0; pt < 4; pt++)                     \
            acc[ct][pt] = __builtin_amdgcn_mfma_f32_32x32x16_bf16(             \
                afr, bfr[pt + dy], acc[ct][pt], 0, 0, 0);                      \
        }                                                                      \
      }                                                                        \
    }                                                                          \
  }

// ---- per-thread X staging source offsets (within-plane shorts, ci=0) ----
#define CONV_XPRE()                                                            \
  int xsrc[5];                                                                 \
  _Pragma("unroll") for (int k5 = 0; k5 < 5; k5++) {                           \
    int u = (wv + 4 * k5) * 64 + lane;                                         \
    if (u > 1223) u = 1223;                                                    \
    int uhi = (u >= 612) ? 1 : 0;                                              \
    int p2 = u - uhi * 612;                                                    \
    int r = p2 / 34, c = p2 - r * 34;                                          \
    int hh = h0 + r; if (hh > Hpad - 1) hh = Hpad - 1;                         \
    int ww = w0 + c; if (ww > Wp - 1) ww = Wp - 1;                             \
    xsrc[k5] = (hh * Wp + ww) * 256 + uhi * 8;                                 \
  }

// ---- double-buffered 16-chunk K-loop ----
#define CONV_MAIN_LOOP(INP, WBLOB, CB)                                         \
  {                                                                            \
    CONV_STAGE(INP, WBLOB, CB, 0, lds_w[0], lds_x[0])                          \
    __syncthreads();                                                           \
    _Pragma("unroll 1") for (int c = 0; c < 16; c += 2) {                      \
      CONV_STAGE(INP, WBLOB, CB, c + 1, lds_w[1], lds_x[1])                    \
      CONV_COMPUTE(lds_w[0], lds_x[0])                                         \
      __syncthreads();                                                         \
      if (c + 2 < 16) CONV_STAGE(INP, WBLOB, CB, c + 2, lds_w[0], lds_x[0])    \
      CONV_COMPUTE(lds_w[1], lds_x[1])                                         \
      __syncthreads();                                                         \
    }                                                                          \
  }

// ---- tower conv layer (bf16 in -> bf16 out, +bias, ReLU) ----
__global__ __launch_bounds__(256, 2) void conv_tower_mfma(
    const unsigned short* __restrict__ xin, unsigned short* __restrict__ xout,
    const unsigned short* __restrict__ wblob_cls,
    const unsigned short* __restrict__ wblob_box,
    const float* __restrict__ bias_cls, const float* __restrict__ bias_box,
    int in_n_stride, int in_tw_stride) {
  __shared__ __align__(16) unsigned short lds_w[2][9216];
  __shared__ __align__(16) unsigned short lds_x[2][10240];
  const int t = threadIdx.x, lane = t & 63, wv = t >> 6;
  const int hi = lane >> 5, col31 = lane & 31;
  const int hixx = hi * 612;
  const int hi32p = hi * 32 + col31;
  const int wrow = wv * 4;
  int l, h0, w0, H, W, Wp, loff;
  decode_tile(blockIdx.x, l, h0, w0, H, W, Wp, loff);
  const int Hpad = H + 2;
  const int cb = blockIdx.y;
  const int n = blockIdx.z >> 1, tw = blockIdx.z & 1;
  const unsigned short* wblob = tw ? wblob_box : wblob_cls;
  const float* bias = tw ? bias_box : bias_cls;
  const unsigned short* inp =
      xin + ((size_t)n * in_n_stride + (size_t)tw * in_tw_stride + loff) * 256;
  unsigned short* outp = xout + ((size_t)(n * 2 + tw) * LVLTOT + loff) * 256;

  floatx16 acc[2][4];
#pragma unroll
  for (int i = 0; i < 2; i++)
#pragma unroll
    for (int jj = 0; jj < 4; jj++)
#pragma unroll
      for (int e = 0; e < 16; e++) acc[i][jj][e] = 0.f;

  CONV_XPRE()
  CONV_MAIN_LOOP(inp, wblob, cb)

  // epilogue: +bias, relu, bf16; C/D row = (reg&3)+8*(reg>>2)+4*hi
#pragma unroll
  for (int ct = 0; ct < 2; ct++) {
#pragma unroll
    for (int pt = 0; pt < 4; pt++) {
      int h = h0 + wv * 4 + pt;
      int w_ = w0 + col31;
      if (h < H && w_ < W) {
#pragma unroll
        for (int g8 = 0; g8 < 4; g8++) {
          int co0 = cb * 64 + ct * 32 + g8 * 8 + hi * 4;
          floatx4 bb = *(const floatx4*)(bias + co0);
          unsigned short pk[4];
#pragma unroll
          for (int rg = 0; rg < 4; rg++)
            pk[rg] = f2bf(fmaxf(acc[ct][pt][g8 * 4 + rg] + bb[rg], 0.f));
          *(unsigned long long*)(outp +
              ((size_t)(h + 1) * Wp + (w_ + 1)) * 256 + co0) =
              *(unsigned long long*)pk;
        }
      }
    }
  }
}

// ---- merged final conv (y<12: cls cb=y; y==12: box), permuted fp32 out ----
__global__ __launch_bounds__(256, 2) void conv_final_mfma(
    const unsigned short* __restrict__ xin, float* __restrict__ out,
    const unsigned short* __restrict__ wblob_cls,
    const unsigned short* __restrict__ wblob_box,
    const float* __restrict__ bias_cls, const float* __restrict__ bias_box) {
  __shared__ __align__(16) unsigned short lds_w[2][9216];
  __shared__ __align__(16) unsigned short lds_x[2][10240];
  const int t = threadIdx.x, lane = t & 63, wv = t >> 6;
  const int hi = lane >> 5, col31 = lane & 31;
  const int hixx = hi * 612;
  const int hi32p = hi * 32 + col31;
  const int wrow = wv * 4;
  int l, h0, w0, H, W, Wp, loff;
  decode_tile(blockIdx.x, l, h0, w0, H, W, Wp, loff);
  const int Hpad = H + 2;
  const int yb = blockIdx.y;
  const bool is_cls = yb < 12;
  const int cb = is_cls ? yb : 0;
  const int tw = is_cls ? 0 : 1;
  const int Cout = is_cls ? 720 : 36;
  const unsigned short* wblob = is_cls ? wblob_cls : wblob_box;
  const float* bias = is_cls ? bias_cls : bias_box;
  const int n = blockIdx.z;
  const int RB[5] = {0, 90000, 112500, 118125, 119646};
  const unsigned short* inp = xin + ((size_t)(n * 2 + tw) * LVLTOT + loff) * 256;

  floatx16 acc[2][4];
#pragma unroll
  for (int i = 0; i < 2; i++)
#pragma unroll
    for (int jj = 0; jj < 4; jj++)
#pragma unroll
      for (int e = 0; e < 16; e++) acc[i][jj][e] = 0.f;

  CONV_XPRE()
  CONV_MAIN_LOOP(inp, wblob, cb)

#pragma unroll
  for (int ct = 0; ct < 2; ct++) {
#pragma unroll
    for (int g8 = 0; g8 < 4; g8++) {
      int co0 = cb * 64 + ct * 32 + g8 * 8 + hi * 4;
      if (co0 >= Cout) continue;
      floatx4 bb = *(const floatx4*)(bias + co0);
      int a = is_cls ? (co0 / 80) : (co0 >> 2);
      int col0 = is_cls ? (co0 - a * 80) : 80;
#pragma unroll
      for (int pt = 0; pt < 4; pt++) {
        int h = h0 + wv * 4 + pt;
        int w_ = w0 + col31;
        if (h < H && w_ < W) {
          size_t ridx = (size_t)RB[l] + ((size_t)h * W + w_) * 9 + a;
          floatx4 v;
#pragma unroll
          for (int rg = 0; rg < 4; rg++) v[rg] = acc[ct][pt][g8 * 4 + rg] + bb[rg];
          *(floatx4*)(out + ((size_t)n * 120087 + ridx) * 84 + col0) = v;
        }
      }
    }
  }
}

extern "C" void kernel_launch(void* const* d_in, const int* in_sizes, int n_in,
                              void* d_out, int out_size, void* d_ws,
                              size_t ws_size, hipStream_t stream) {
  // ws layout (bytes):
  //   bufB [0, 28964864)    (X0 aliased to bufB planes 2,3: dead after layer 1)
  //   X0   [14482432, 28964864)
  //   bufA [28964864, 57929728)
  //   tower blobs 8 x 1179648 at 57929728 (cls0..3, box0..3)
  //   cls final blob 3538944 at 67366912; box final blob 294912 at 70905856
  char* ws = (char*)d_ws;
  unsigned short* bufB = (unsigned short*)(ws);
  unsigned short* X0 = (unsigned short*)(ws + 14482432);
  unsigned short* bufA = (unsigned short*)(ws + 28964864);
  unsigned short* tb[8];
  for (int i = 0; i < 8; i++)
    tb[i] = (unsigned short*)(ws + 57929728 + (size_t)i * 1179648);
  unsigned short* fb_cls = (unsigned short*)(ws + 67366912);
  unsigned short* fb_box = (unsigned short*)(ws + 70905856);

  float* out = (float*)d_out;

  PrepArgs pa;
  for (int i = 0; i < 5; i++) pa.f[i] = (const float*)d_in[i];
  for (int i = 0; i < 4; i++) {
    pa.w[i] = (const float*)d_in[5 + 2 * i];       // cls_w0..3
    pa.w[4 + i] = (const float*)d_in[13 + 2 * i];  // box_w0..3
    pa.wdst[i] = tb[i];
    pa.wdst[4 + i] = tb[4 + i];
    pa.cout[i] = pa.cout[4 + i] = 256;
  }
  pa.w[8] = (const float*)d_in[21]; pa.wdst[8] = fb_cls; pa.cout[8] = 720;
  pa.w[9] = (const float*)d_in[23]; pa.wdst[9] = fb_box; pa.cout[9] = 36;
  // padded-co block counts: towers 256 each, cls 768, box 64
  int off = 0;
  for (int i = 0; i < 8; i++) { pa.wblk_off[i] = off; off += 256; }
  pa.wblk_off[8] = off; off += 768;
  pa.wblk_off[9] = off; off += 64;
  pa.wblk_off[10] = off;  // 2880
  pa.x0 = X0;
  pa.bufA = bufA;
  pa.bufB = bufB;

  prep<<<dim3(4770), 256, 0, stream>>>(pa);

  const float *cls_b[4], *box_b[4];
  for (int i = 0; i < 4; i++) {
    cls_b[i] = (const float*)d_in[6 + 2 * i];
    box_b[i] = (const float*)d_in[14 + 2 * i];
  }

  dim3 gt(40, 4, 4);
  conv_tower_mfma<<<gt, 256, 0, stream>>>(X0, bufA, tb[0], tb[4], cls_b[0],
                                          box_b[0], LVLTOT, 0);
  conv_tower_mfma<<<gt, 256, 0, stream>>>(bufA, bufB, tb[1], tb[5], cls_b[1],
                                          box_b[1], 2 * LVLTOT, LVLTOT);
  conv_tower_mfma<<<gt, 256, 0, stream>>>(bufB, bufA, tb[2], tb[6], cls_b[2],
                                          box_b[2], 2 * LVLTOT, LVLTOT);
  conv_tower_mfma<<<gt, 256, 0, stream>>>(bufA, bufB, tb[3], tb[7], cls_b[3],
                                          box_b[3], 2 * LVLTOT, LVLTOT);

  conv_final_mfma<<<dim3(40, 13, 2), 256, 0, stream>>>(
      bufB, out, fb_cls, fb_box, (const float*)d_in[22], (const float*)d_in[24]);
}

// Round 3
// 775.462 us; speedup vs baseline: 1.1016x; 1.0187x over previous
//
#include <hip/hip_runtime.h>

// RetinaNet head via bf16 MFMA implicit-GEMM — R4 structure.
// Activations: padded NHWC bf16 [plane][(H+2)(W+2)][256], zero borders.
// R4 = R3 geometry (32x32x16 MFMA, ci-chunk=16, double-buffered 77824B LDS,
// 2 blocks/CU) + T4 COUNTED-VMCNT pipeline (m218: counted vs drain-0 is the
// entire gain of double-buffering):
//   prologue: stage(0); stage(1); vmcnt(10); barrier
//   chunk c:  compute(c); barrier; stage(c+2); s_waitcnt vmcnt(10); barrier
// Raw s_barrier (no implicit vmcnt(0) drain, unlike __syncthreads); each wave
// issues EXACTLY 10 global_load_lds per stage (waves 2,3 dup one W-group) so
// the counted wait releases when stage(c+1) is done while stage(c+2) stays in
// flight across the barrier and the whole next compute phase.
// W blob layout: [cb][chunk16][tap][ct(2)][hi(2)][co32][8ci].
// X LDS layout: [hi(2)][18 rows][34 cols][8ci] (1224 units + pad to 1280).

typedef __attribute__((ext_vector_type(8))) short short8;
typedef __attribute__((ext_vector_type(4))) float floatx4;
typedef __attribute__((ext_vector_type(16))) float floatx16;

#define LVLTOT 14143  // sum of padded (H+2)(W+2) over 5 levels

__device__ __forceinline__ unsigned short f2bf(float f) {
  unsigned int u = __float_as_uint(f);
  unsigned int r = (u + 0x7fffu + ((u >> 16) & 1u)) >> 16;
  return (unsigned short)r;
}

__device__ __forceinline__ void gload_lds16(const void* g, void* l) {
  __builtin_amdgcn_global_load_lds(
      (const __attribute__((address_space(1))) unsigned int*)g,
      (__attribute__((address_space(3))) unsigned int*)l, 16, 0, 0);
}

// ================= fused prep: xprep + wprep + border zero =================
struct PrepArgs {
  const float* f[5];
  const float* w[10];
  unsigned short* wdst[10];
  int wblk_off[11];
  int cout[10];
  unsigned short* x0;
  unsigned short* bufA;
  unsigned short* bufB;
};

__global__ __launch_bounds__(256) void prep(PrepArgs A) {
  static const int Ht[5] = {100, 50, 25, 13, 7};
  static const int Wpt[5] = {102, 52, 27, 15, 9};
  static const int LOFFt[5] = {0, 10404, 13108, 13837, 14062};
  __shared__ float ts[32][33];
  const int bid = blockIdx.x;
  const int t = threadIdx.x;

  if (bid < 1090) {
    // ---- xprep: one 32-px row-strip, all 256 ch, one n ----
    int sid = bid % 545, n = bid / 545;
    int l, h, wb;
    if (sid < 400)      { l = 0; h = sid >> 2; wb = sid & 3; }
    else if (sid < 500) { l = 1; h = (sid - 400) >> 1; wb = (sid - 400) & 1; }
    else if (sid < 525) { l = 2; h = sid - 500; wb = 0; }
    else if (sid < 538) { l = 3; h = sid - 525; wb = 0; }
    else                { l = 4; h = sid - 538; wb = 0; }
    const float* f = A.f[l];
    int H = Ht[l], W = H, Wp = Wpt[l], loff = LOFFt[l];
    int w0 = wb * 32;
    for (int s = 0; s < 8; s++) {
      int ch0 = s * 32;
      __syncthreads();
#pragma unroll
      for (int r4 = 0; r4 < 4; r4++) {
        int ch = ch0 + (t >> 5) + r4 * 8;
        int px = w0 + (t & 31);
        float v = 0.f;
        if (px < W) v = f[(((size_t)n * 256 + ch) * H + h) * W + px];
        ts[(t >> 5) + r4 * 8][t & 31] = v;
      }
      __syncthreads();
      int pxl = t >> 3, c4 = t & 7;
      if (w0 + pxl < W) {
        unsigned short pk[4];
#pragma unroll
        for (int k = 0; k < 4; k++) pk[k] = f2bf(ts[c4 * 4 + k][pxl]);
        *(unsigned long long*)(A.x0 +
            ((size_t)n * LVLTOT + loff + (size_t)(h + 1) * Wp + (w0 + pxl + 1)) *
                256 + ch0 + c4 * 4) = *(unsigned long long*)pk;
      }
    }
    return;
  }

  if (bid < 3970) {
    // ---- wprep: block = one padded co of one tensor; thread = ci ----
    // Layout for 32x32x16: [cb][chunk(ci>>4)][tap][ct][hi][co32][8]
    int b2 = bid - 1090;
    int tix = 0;
    while (b2 >= A.wblk_off[tix + 1]) tix++;
    int co = b2 - A.wblk_off[tix];
    int ci = t;
    bool valid = co < A.cout[tix];
    const float* w = A.w[tix];
    unsigned short* dst = A.wdst[tix];
    int cb = co >> 6, ct = (co >> 5) & 1, co32 = co & 31;
    int chunk = ci >> 4, hi = (ci >> 3) & 1, j = ci & 7;
#pragma unroll
    for (int tap = 0; tap < 9; tap++) {
      float v = valid ? w[((size_t)co * 256 + ci) * 9 + tap] : 0.f;
      dst[((((size_t)(cb * 16 + chunk) * 9 + tap) * 2 + ct) * 2 + hi) * 256 +
          co32 * 8 + j] = f2bf(v);
    }
    return;
  }

  // ---- border zero: items = 800 border px x 32 octs per plane ----
  {
    static const int BCUM[6] = {0, 404, 608, 712, 768, 800};
    int b3 = bid - 3970;             // [0,800): plane = b3/100
    int plane = b3 / 100;
    int item = (b3 % 100) * 256 + t; // [0,25600)
    int pxi = item >> 5, oct = item & 31;
    if (pxi >= 800) return;
    int l = 0;
    while (pxi >= BCUM[l + 1]) l++;
    int j = pxi - BCUM[l];
    int Wp = Wpt[l];
    int r, c;
    if (j < Wp)            { r = 0; c = j; }
    else if (j < 2 * Wp)   { r = Wp - 1; c = j - Wp; }
    else { int k = j - 2 * Wp; r = 1 + (k >> 1); c = (k & 1) ? Wp - 1 : 0; }
    size_t px = (size_t)LOFFt[l] + (size_t)r * Wp + c;
    unsigned short* base = (plane < 4)
                               ? (A.bufA + (size_t)plane * LVLTOT * 256)
                               : (A.bufB + (size_t)(plane - 4) * LVLTOT * 256);
    floatx4 z;
    z[0] = z[1] = z[2] = z[3] = 0.f;
    *(floatx4*)(base + px * 256 + oct * 8) = z;
  }
}

// ---- tile decode (40 tiles of 16 rows x 32 cols over 5 levels) ----
__device__ __forceinline__ void decode_tile(int tile, int& l, int& h0, int& w0,
                                            int& H, int& W, int& Wp, int& loff) {
  const int Ht[5] = {100, 50, 25, 13, 7};
  const int Wpt[5] = {102, 52, 27, 15, 9};
  const int TXt[5] = {4, 2, 1, 1, 1};
  const int LOFFt[5] = {0, 10404, 13108, 13837, 14062};
  int tloc;
  if (tile < 28) { l = 0; tloc = tile; }
  else if (tile < 36) { l = 1; tloc = tile - 28; }
  else if (tile < 38) { l = 2; tloc = tile - 36; }
  else if (tile < 39) { l = 3; tloc = tile - 38; }
  else { l = 4; tloc = 0; }
  H = Ht[l]; W = H; Wp = Wpt[l]; loff = LOFFt[l];
  int ty = tloc / TXt[l], tx = tloc - ty * TXt[l];
  h0 = ty * 16; w0 = tx * 32;
}

// ---- staging of one ci-chunk(16): EXACTLY 10 global_load_lds per wave ----
// W: 18 groups of 64x16B (waves 2,3 re-issue their first group as a dup so
// every wave's vmcnt contribution is uniform); X: 20 groups.
#define CONV_STAGE(INP, WBLOB, CB, CH, LW, LX)                                 \
  {                                                                            \
    const unsigned short* wsrc =                                               \
        (WBLOB) + ((size_t)((CB) * 16 + (CH))) * 9216;                         \
    _Pragma("unroll") for (int k5 = 0; k5 < 5; k5++) {                         \
      int g = wv + 4 * k5;                                                     \
      if (g >= 18) g = wv;                                                     \
      gload_lds16(wsrc + g * 512 + lane * 8, (LW) + g * 512);                  \
    }                                                                          \
    _Pragma("unroll") for (int k5 = 0; k5 < 5; k5++) {                         \
      int gx = wv + 4 * k5;                                                    \
      gload_lds16((INP) + xsrc[k5] + (CH) * 16, (LX) + gx * 512);              \
    }                                                                          \
  }

// ---- compute of one ci-chunk(16): 18 A + 18 B ds_read_b128, 72 MFMA ----
// (needs: wv, hixx, wrow, col31, hi32p, acc[2][4])
#define CONV_COMPUTE(LW, LX)                                                   \
  {                                                                            \
    const short8* xw = (const short8*)(LW);                                    \
    const short8* xx = (const short8*)(LX);                                    \
    _Pragma("unroll") for (int dx = 0; dx < 3; dx++) {                         \
      short8 bfr[6];                                                           \
      _Pragma("unroll") for (int rb = 0; rb < 6; rb++)                         \
        bfr[rb] = xx[hixx + (wrow + rb) * 34 + dx + col31];                    \
      _Pragma("unroll") for (int dy = 0; dy < 3; dy++) {                       \
        const int tap = dy * 3 + dx;                                           \
        _Pragma("unroll") for (int ct = 0; ct < 2; ct++) {                     \
          short8 afr = xw[(tap * 2 + ct) * 64 + hi32p];                        \
          _Pragma("unroll") for (int pt = 0; pt < 4; pt++)                     \
            acc[ct][pt] = __builtin_amdgcn_mfma_f32_32x32x16_bf16(             \
                afr, bfr[pt + dy], acc[ct][pt], 0, 0, 0);                      \
        }                                                                      \
      }                                                                        \
    }                                                                          \
  }

// ---- per-thread X staging source offsets (within-plane shorts, ci=0) ----
#define CONV_XPRE()                                                            \
  int xsrc[5];                                                                 \
  _Pragma("unroll") for (int k5 = 0; k5 < 5; k5++) {                           \
    int u = (wv + 4 * k5) * 64 + lane;                                         \
    if (u > 1223) u = 1223;                                                    \
    int uhi = (u >= 612) ? 1 : 0;                                              \
    int p2 = u - uhi * 612;                                                    \
    int r = p2 / 34, c = p2 - r * 34;                                          \
    int hh = h0 + r; if (hh > Hpad - 1) hh = Hpad - 1;                         \
    int ww = w0 + c; if (ww > Wp - 1) ww = Wp - 1;                             \
    xsrc[k5] = (hh * Wp + ww) * 256 + uhi * 8;                                 \
  }

// ---- counted-vmcnt sync primitives (T4) ----
#define VM_WAIT10 asm volatile("s_waitcnt vmcnt(10)" ::: "memory")
#define VM_WAIT0 asm volatile("s_waitcnt vmcnt(0)" ::: "memory")
#define BAR() __builtin_amdgcn_s_barrier()
#define SCHED_FENCE() __builtin_amdgcn_sched_barrier(0)

// ---- counted-vmcnt double-buffered 16-chunk K-loop ----
// Invariant entering chunk c: buf[c&1] holds stage(c) (waited), stage(c+1)'s
// 10 loads are in flight. Main loop NEVER drains vmcnt to 0 (tail only).
#define CONV_MAIN_LOOP(INP, WBLOB, CB)                                         \
  {                                                                            \
    CONV_STAGE(INP, WBLOB, CB, 0, lds_w[0], lds_x[0])                          \
    CONV_STAGE(INP, WBLOB, CB, 1, lds_w[1], lds_x[1])                          \
    VM_WAIT10;                                                                 \
    BAR();                                                                     \
    SCHED_FENCE();                                                             \
    _Pragma("unroll 1") for (int c = 0; c < 16; c += 2) {                      \
      CONV_COMPUTE(lds_w[0], lds_x[0])                                         \
      SCHED_FENCE();                                                           \
      BAR(); /* all waves done reading buf0 */                                 \
      if (c < 14) {                                                            \
        CONV_STAGE(INP, WBLOB, CB, c + 2, lds_w[0], lds_x[0])                  \
        VM_WAIT10; /* stage(c+1) landed; stage(c+2) stays in flight */         \
      } else {                                                                 \
        VM_WAIT0; /* tail: ensure stage(15) landed */                          \
      }                                                                        \
      BAR();                                                                   \
      SCHED_FENCE();                                                           \
      CONV_COMPUTE(lds_w[1], lds_x[1])                                         \
      SCHED_FENCE();                                                           \
      BAR(); /* all waves done reading buf1 */                                 \
      if (c < 13) {                                                            \
        CONV_STAGE(INP, WBLOB, CB, c + 3, lds_w[1], lds_x[1])                  \
        VM_WAIT10;                                                             \
      } else {                                                                 \
        VM_WAIT0;                                                              \
      }                                                                        \
      BAR();                                                                   \
      SCHED_FENCE();                                                           \
    }                                                                          \
  }

// ---- tower conv layer (bf16 in -> bf16 out, +bias, ReLU) ----
__global__ __launch_bounds__(256, 2) void conv_tower_mfma(
    const unsigned short* __restrict__ xin, unsigned short* __restrict__ xout,
    const unsigned short* __restrict__ wblob_cls,
    const unsigned short* __restrict__ wblob_box,
    const float* __restrict__ bias_cls, const float* __restrict__ bias_box,
    int in_n_stride, int in_tw_stride) {
  __shared__ __align__(16) unsigned short lds_w[2][9216];
  __shared__ __align__(16) unsigned short lds_x[2][10240];
  const int t = threadIdx.x, lane = t & 63, wv = t >> 6;
  const int hi = lane >> 5, col31 = lane & 31;
  const int hixx = hi * 612;
  const int hi32p = hi * 32 + col31;
  const int wrow = wv * 4;
  int l, h0, w0, H, W, Wp, loff;
  decode_tile(blockIdx.x, l, h0, w0, H, W, Wp, loff);
  const int Hpad = H + 2;
  const int cb = blockIdx.y;
  const int n = blockIdx.z >> 1, tw = blockIdx.z & 1;
  const unsigned short* wblob = tw ? wblob_box : wblob_cls;
  const float* bias = tw ? bias_box : bias_cls;
  const unsigned short* inp =
      xin + ((size_t)n * in_n_stride + (size_t)tw * in_tw_stride + loff) * 256;
  unsigned short* outp = xout + ((size_t)(n * 2 + tw) * LVLTOT + loff) * 256;

  floatx16 acc[2][4];
#pragma unroll
  for (int i = 0; i < 2; i++)
#pragma unroll
    for (int jj = 0; jj < 4; jj++)
#pragma unroll
      for (int e = 0; e < 16; e++) acc[i][jj][e] = 0.f;

  CONV_XPRE()
  CONV_MAIN_LOOP(inp, wblob, cb)

  // epilogue: +bias, relu, bf16; C/D row = (reg&3)+8*(reg>>2)+4*hi
#pragma unroll
  for (int ct = 0; ct < 2; ct++) {
#pragma unroll
    for (int pt = 0; pt < 4; pt++) {
      int h = h0 + wv * 4 + pt;
      int w_ = w0 + col31;
      if (h < H && w_ < W) {
#pragma unroll
        for (int g8 = 0; g8 < 4; g8++) {
          int co0 = cb * 64 + ct * 32 + g8 * 8 + hi * 4;
          floatx4 bb = *(const floatx4*)(bias + co0);
          unsigned short pk[4];
#pragma unroll
          for (int rg = 0; rg < 4; rg++)
            pk[rg] = f2bf(fmaxf(acc[ct][pt][g8 * 4 + rg] + bb[rg], 0.f));
          *(unsigned long long*)(outp +
              ((size_t)(h + 1) * Wp + (w_ + 1)) * 256 + co0) =
              *(unsigned long long*)pk;
        }
      }
    }
  }
}

// ---- merged final conv (y<12: cls cb=y; y==12: box), permuted fp32 out ----
__global__ __launch_bounds__(256, 2) void conv_final_mfma(
    const unsigned short* __restrict__ xin, float* __restrict__ out,
    const unsigned short* __restrict__ wblob_cls,
    const unsigned short* __restrict__ wblob_box,
    const float* __restrict__ bias_cls, const float* __restrict__ bias_box) {
  __shared__ __align__(16) unsigned short lds_w[2][9216];
  __shared__ __align__(16) unsigned short lds_x[2][10240];
  const int t = threadIdx.x, lane = t & 63, wv = t >> 6;
  const int hi = lane >> 5, col31 = lane & 31;
  const int hixx = hi * 612;
  const int hi32p = hi * 32 + col31;
  const int wrow = wv * 4;
  int l, h0, w0, H, W, Wp, loff;
  decode_tile(blockIdx.x, l, h0, w0, H, W, Wp, loff);
  const int Hpad = H + 2;
  const int yb = blockIdx.y;
  const bool is_cls = yb < 12;
  const int cb = is_cls ? yb : 0;
  const int tw = is_cls ? 0 : 1;
  const int Cout = is_cls ? 720 : 36;
  const unsigned short* wblob = is_cls ? wblob_cls : wblob_box;
  const float* bias = is_cls ? bias_cls : bias_box;
  const int n = blockIdx.z;
  const int RB[5] = {0, 90000, 112500, 118125, 119646};
  const unsigned short* inp = xin + ((size_t)(n * 2 + tw) * LVLTOT + loff) * 256;

  floatx16 acc[2][4];
#pragma unroll
  for (int i = 0; i < 2; i++)
#pragma unroll
    for (int jj = 0; jj < 4; jj++)
#pragma unroll
      for (int e = 0; e < 16; e++) acc[i][jj][e] = 0.f;

  CONV_XPRE()
  CONV_MAIN_LOOP(inp, wblob, cb)

#pragma unroll
  for (int ct = 0; ct < 2; ct++) {
#pragma unroll
    for (int g8 = 0; g8 < 4; g8++) {
      int co0 = cb * 64 + ct * 32 + g8 * 8 + hi * 4;
      if (co0 >= Cout) continue;
      floatx4 bb = *(const floatx4*)(bias + co0);
      int a = is_cls ? (co0 / 80) : (co0 >> 2);
      int col0 = is_cls ? (co0 - a * 80) : 80;
#pragma unroll
      for (int pt = 0; pt < 4; pt++) {
        int h = h0 + wv * 4 + pt;
        int w_ = w0 + col31;
        if (h < H && w_ < W) {
          size_t ridx = (size_t)RB[l] + ((size_t)h * W + w_) * 9 + a;
          floatx4 v;
#pragma unroll
          for (int rg = 0; rg < 4; rg++) v[rg] = acc[ct][pt][g8 * 4 + rg] + bb[rg];
          *(floatx4*)(out + ((size_t)n * 120087 + ridx) * 84 + col0) = v;
        }
      }
    }
  }
}

extern "C" void kernel_launch(void* const* d_in, const int* in_sizes, int n_in,
                              void* d_out, int out_size, void* d_ws,
                              size_t ws_size, hipStream_t stream) {
  // ws layout (bytes):
  //   bufB [0, 28964864)    (X0 aliased to bufB planes 2,3: dead after layer 1)
  //   X0   [14482432, 28964864)
  //   bufA [28964864, 57929728)
  //   tower blobs 8 x 1179648 at 57929728 (cls0..3, box0..3)
  //   cls final blob 3538944 at 67366912; box final blob 294912 at 70905856
  char* ws = (char*)d_ws;
  unsigned short* bufB = (unsigned short*)(ws);
  unsigned short* X0 = (unsigned short*)(ws + 14482432);
  unsigned short* bufA = (unsigned short*)(ws + 28964864);
  unsigned short* tb[8];
  for (int i = 0; i < 8; i++)
    tb[i] = (unsigned short*)(ws + 57929728 + (size_t)i * 1179648);
  unsigned short* fb_cls = (unsigned short*)(ws + 67366912);
  unsigned short* fb_box = (unsigned short*)(ws + 70905856);

  float* out = (float*)d_out;

  PrepArgs pa;
  for (int i = 0; i < 5; i++) pa.f[i] = (const float*)d_in[i];
  for (int i = 0; i < 4; i++) {
    pa.w[i] = (const float*)d_in[5 + 2 * i];       // cls_w0..3
    pa.w[4 + i] = (const float*)d_in[13 + 2 * i];  // box_w0..3
    pa.wdst[i] = tb[i];
    pa.wdst[4 + i] = tb[4 + i];
    pa.cout[i] = pa.cout[4 + i] = 256;
  }
  pa.w[8] = (const float*)d_in[21]; pa.wdst[8] = fb_cls; pa.cout[8] = 720;
  pa.w[9] = (const float*)d_in[23]; pa.wdst[9] = fb_box; pa.cout[9] = 36;
  // padded-co block counts: towers 256 each, cls 768, box 64
  int off = 0;
  for (int i = 0; i < 8; i++) { pa.wblk_off[i] = off; off += 256; }
  pa.wblk_off[8] = off; off += 768;
  pa.wblk_off[9] = off; off += 64;
  pa.wblk_off[10] = off;  // 2880
  pa.x0 = X0;
  pa.bufA = bufA;
  pa.bufB = bufB;

  prep<<<dim3(4770), 256, 0, stream>>>(pa);

  const float *cls_b[4], *box_b[4];
  for (int i = 0; i < 4; i++) {
    cls_b[i] = (const float*)d_in[6 + 2 * i];
    box_b[i] = (const float*)d_in[14 + 2 * i];
  }

  dim3 gt(40, 4, 4);
  conv_tower_mfma<<<gt, 256, 0, stream>>>(X0, bufA, tb[0], tb[4], cls_b[0],
                                          box_b[0], LVLTOT, 0);
  conv_tower_mfma<<<gt, 256, 0, stream>>>(bufA, bufB, tb[1], tb[5], cls_b[1],
                                          box_b[1], 2 * LVLTOT, LVLTOT);
  conv_tower_mfma<<<gt, 256, 0, stream>>>(bufB, bufA, tb[2], tb[6], cls_b[2],
                                          box_b[2], 2 * LVLTOT, LVLTOT);
  conv_tower_mfma<<<gt, 256, 0, stream>>>(bufA, bufB, tb[3], tb[7], cls_b[3],
                                          box_b[3], 2 * LVLTOT, LVLTOT);

  conv_final_mfma<<<dim3(40, 13, 2), 256, 0, stream>>>(
      bufB, out, fb_cls, fb_box, (const float*)d_in[22], (const float*)d_in[24]);
}

// Round 4
// 705.868 us; speedup vs baseline: 1.2102x; 1.0986x over previous
//
#include <hip/hip_runtime.h>

// RetinaNet head via bf16 MFMA implicit-GEMM — R5 structure.
// Activations: padded NHWC bf16 [plane][(H+2)(W+2)][256], zero borders.
// R5 = R1's proven 16x16x32 compute core + m201-style fine-interleaved
// phase schedule (the measured lever: m196/m198 +28-41%; R2/R3/R4 coarse
// splits reproduced m196's null/regression).
// Block: 512 threads (8 waves, 2/SIMD, 1 block/CU), tile 64co x 512px
// (16 rows x 32 cols, halo 18x34=612 px). Wave = 64co x 64px (rows 4R..4R+3,
// cols 16C..16C+15). LDS: double-buffered W(36KB)+X(40KB) = 152KB.
// Per ci-chunk(32), 3 phases (one per tap-col tdx):
//   {6 B + 12 A ds_read_b128 ; ~4 global_load_lds of chunk c+1 ->
//    s_barrier -> lgkmcnt(0)+sched_barrier -> setprio(1) -> 48 MFMA ->
//    setprio(0) -> s_barrier}
// vmcnt(0) only at chunk boundary — every staged load has had 1-3 phases of
// MFMA cover by then (earned drain, not exposed drain).
// W blob layout (R1's): [cb][chunk32][tap][q4][co64][8ci].
// X LDS layout: [q:4][640 px-slots], slot = r*34+c (18x34 used, rest junk).

typedef __attribute__((ext_vector_type(8))) short short8;
typedef __attribute__((ext_vector_type(4))) float floatx4;

#define LVLTOT 14143  // sum of padded (H+2)(W+2) over 5 levels

__device__ __forceinline__ unsigned short f2bf(float f) {
  unsigned int u = __float_as_uint(f);
  unsigned int r = (u + 0x7fffu + ((u >> 16) & 1u)) >> 16;
  return (unsigned short)r;
}

__device__ __forceinline__ void gload_lds16(const void* g, void* l) {
  __builtin_amdgcn_global_load_lds(
      (const __attribute__((address_space(1))) unsigned int*)g,
      (__attribute__((address_space(3))) unsigned int*)l, 16, 0, 0);
}

// ================= fused prep: xprep + wprep + border zero =================
struct PrepArgs {
  const float* f[5];
  const float* w[10];
  unsigned short* wdst[10];
  int wblk_off[11];
  int cout[10];
  unsigned short* x0;
  unsigned short* bufA;
  unsigned short* bufB;
};

__global__ __launch_bounds__(256) void prep(PrepArgs A) {
  static const int Ht[5] = {100, 50, 25, 13, 7};
  static const int Wpt[5] = {102, 52, 27, 15, 9};
  static const int LOFFt[5] = {0, 10404, 13108, 13837, 14062};
  __shared__ float ts[32][33];
  const int bid = blockIdx.x;
  const int t = threadIdx.x;

  if (bid < 1090) {
    // ---- xprep: one 32-px row-strip, all 256 ch, one n ----
    int sid = bid % 545, n = bid / 545;
    int l, h, wb;
    if (sid < 400)      { l = 0; h = sid >> 2; wb = sid & 3; }
    else if (sid < 500) { l = 1; h = (sid - 400) >> 1; wb = (sid - 400) & 1; }
    else if (sid < 525) { l = 2; h = sid - 500; wb = 0; }
    else if (sid < 538) { l = 3; h = sid - 525; wb = 0; }
    else                { l = 4; h = sid - 538; wb = 0; }
    const float* f = A.f[l];
    int H = Ht[l], W = H, Wp = Wpt[l], loff = LOFFt[l];
    int w0 = wb * 32;
    for (int s = 0; s < 8; s++) {
      int ch0 = s * 32;
      __syncthreads();
#pragma unroll
      for (int r4 = 0; r4 < 4; r4++) {
        int ch = ch0 + (t >> 5) + r4 * 8;
        int px = w0 + (t & 31);
        float v = 0.f;
        if (px < W) v = f[(((size_t)n * 256 + ch) * H + h) * W + px];
        ts[(t >> 5) + r4 * 8][t & 31] = v;
      }
      __syncthreads();
      int pxl = t >> 3, c4 = t & 7;
      if (w0 + pxl < W) {
        unsigned short pk[4];
#pragma unroll
        for (int k = 0; k < 4; k++) pk[k] = f2bf(ts[c4 * 4 + k][pxl]);
        *(unsigned long long*)(A.x0 +
            ((size_t)n * LVLTOT + loff + (size_t)(h + 1) * Wp + (w0 + pxl + 1)) *
                256 + ch0 + c4 * 4) = *(unsigned long long*)pk;
      }
    }
    return;
  }

  if (bid < 3970) {
    // ---- wprep (R1 16x16 layout): [cb][chunk32][tap][q4][co64][8ci] ----
    int b2 = bid - 1090;
    int tix = 0;
    while (b2 >= A.wblk_off[tix + 1]) tix++;
    int co = b2 - A.wblk_off[tix];
    int ci = t;
    bool valid = co < A.cout[tix];
    const float* w = A.w[tix];
    unsigned short* dst = A.wdst[tix];
    int cb = co >> 6, col = co & 63, chk = ci >> 5, qd = (ci >> 3) & 3, j = ci & 7;
#pragma unroll
    for (int tap = 0; tap < 9; tap++) {
      float v = valid ? w[((size_t)co * 256 + ci) * 9 + tap] : 0.f;
      dst[((((size_t)(cb * 8 + chk) * 9 + tap) * 4 + qd) * 64 + col) * 8 + j] =
          f2bf(v);
    }
    return;
  }

  // ---- border zero: items = 800 border px x 32 octs per plane ----
  {
    static const int BCUM[6] = {0, 404, 608, 712, 768, 800};
    int b3 = bid - 3970;             // [0,800): plane = b3/100
    int plane = b3 / 100;
    int item = (b3 % 100) * 256 + t; // [0,25600)
    int pxi = item >> 5, oct = item & 31;
    if (pxi >= 800) return;
    int l = 0;
    while (pxi >= BCUM[l + 1]) l++;
    int j = pxi - BCUM[l];
    int Wp = Wpt[l];
    int r, c;
    if (j < Wp)            { r = 0; c = j; }
    else if (j < 2 * Wp)   { r = Wp - 1; c = j - Wp; }
    else { int k = j - 2 * Wp; r = 1 + (k >> 1); c = (k & 1) ? Wp - 1 : 0; }
    size_t px = (size_t)LOFFt[l] + (size_t)r * Wp + c;
    unsigned short* base = (plane < 4)
                               ? (A.bufA + (size_t)plane * LVLTOT * 256)
                               : (A.bufB + (size_t)(plane - 4) * LVLTOT * 256);
    floatx4 z;
    z[0] = z[1] = z[2] = z[3] = 0.f;
    *(floatx4*)(base + px * 256 + oct * 8) = z;
  }
}

// ---- tile decode (40 tiles of 16 rows x 32 cols over 5 levels) ----
__device__ __forceinline__ void decode_tile(int tile, int& l, int& h0, int& w0,
                                            int& H, int& W, int& Wp, int& loff) {
  const int Ht[5] = {100, 50, 25, 13, 7};
  const int Wpt[5] = {102, 52, 27, 15, 9};
  const int TXt[5] = {4, 2, 1, 1, 1};
  const int LOFFt[5] = {0, 10404, 13108, 13837, 14062};
  int tloc;
  if (tile < 28) { l = 0; tloc = tile; }
  else if (tile < 36) { l = 1; tloc = tile - 28; }
  else if (tile < 38) { l = 2; tloc = tile - 36; }
  else if (tile < 39) { l = 3; tloc = tile - 38; }
  else { l = 4; tloc = 0; }
  H = Ht[l]; W = H; Wp = Wpt[l]; loff = LOFFt[l];
  int ty = tloc / TXt[l], tx = tloc - ty * TXt[l];
  h0 = ty * 16; w0 = tx * 32;
}

// ---- sync primitives ----
#define BARX() __builtin_amdgcn_s_barrier()
#define SFEN() __builtin_amdgcn_sched_barrier(0)
#define LGKM0() asm volatile("s_waitcnt lgkmcnt(0)" ::: "memory")
#define VMC0() asm volatile("s_waitcnt vmcnt(0)" ::: "memory")

// ---- one phase: reads(P) ; stage-slice ; bar ; wait ; MFMA x48 ----
// needs in scope: lw8, lx8 (short8* of current bufs), q, n16, R4, cwn,
// acc[4][4] (floatx4)
#define CONV_PHASE(P, STAGE)                                                   \
  {                                                                            \
    short8 bfr[6];                                                             \
    _Pragma("unroll") for (int rb = 0; rb < 6; rb++)                           \
      bfr[rb] = lx8[q * 640 + (R4 + rb) * 34 + cwn + (P)];                     \
    short8 afr[3][4];                                                          \
    _Pragma("unroll") for (int ty_ = 0; ty_ < 3; ty_++)                        \
      _Pragma("unroll") for (int cA = 0; cA < 4; cA++)                         \
        afr[ty_][cA] = lw8[((ty_ * 3 + (P)) * 4 + q) * 64 + cA * 16 + n16];    \
    STAGE                                                                      \
    SFEN();                                                                    \
    BARX();                                                                    \
    LGKM0();                                                                   \
    SFEN();                                                                    \
    __builtin_amdgcn_s_setprio(1);                                             \
    _Pragma("unroll") for (int ty_ = 0; ty_ < 3; ty_++)                        \
      _Pragma("unroll") for (int cA = 0; cA < 4; cA++)                         \
        _Pragma("unroll") for (int rr = 0; rr < 4; rr++)                       \
          acc[cA][rr] = __builtin_amdgcn_mfma_f32_16x16x32_bf16(               \
              afr[ty_][cA], bfr[rr + ty_], acc[cA][rr], 0, 0, 0);              \
    __builtin_amdgcn_s_setprio(0);                                             \
    SFEN();                                                                    \
  }

#define SG_X(K, CH32, DST)                                                     \
  gload_lds16((INP_) + xsrc[K] + (CH32),                                       \
              (DST) + ((size_t)qx * 640 + (sgb + (K)) * 64) * 8)
#define SG_W(K, SRC, DST)                                                      \
  {                                                                            \
    int g_ = wv + 8 * (K);                                                     \
    if (g_ < 36)                                                               \
      gload_lds16((SRC) + (size_t)g_ * 512 + lane * 8,                         \
                  (DST) + (size_t)g_ * 512);                                   \
  }

// ---- main loop: 8 ci-chunks x 3 phases, double-buffered, earned vmcnt ----
#define CONV_MAIN_LOOP(INP, WBLOB, CB)                                         \
  {                                                                            \
    const unsigned short* INP_ = (INP);                                        \
    const int qx = wv & 3, sgb = (wv >> 2) * 5;                                \
    int xsrc[5];                                                               \
    _Pragma("unroll") for (int k = 0; k < 5; k++) {                            \
      int p = (sgb + k) * 64 + lane;                                           \
      if (p > 611) p = 611;                                                    \
      int r_ = p / 34, c_ = p - r_ * 34;                                       \
      int hh = h0 + r_; if (hh > Hpad - 1) hh = Hpad - 1;                      \
      int ww = w0 + c_; if (ww > Wp - 1) ww = Wp - 1;                          \
      xsrc[k] = (hh * Wp + ww) * 256 + qx * 8;                                 \
    }                                                                          \
    unsigned short* lwc = &lds_w[0][0];                                        \
    unsigned short* lwn = &lds_w[1][0];                                        \
    unsigned short* lxc = &lds_x[0][0];                                        \
    unsigned short* lxn = &lds_x[1][0];                                        \
    {                                                                          \
      const unsigned short* wsrc0 = (WBLOB) + (size_t)((CB) * 8) * 18432;      \
      _Pragma("unroll") for (int k = 0; k < 5; k++) SG_X(k, 0, lxc);           \
      _Pragma("unroll") for (int k = 0; k < 5; k++) SG_W(k, wsrc0, lwc);       \
    }                                                                          \
    VMC0();                                                                    \
    BARX();                                                                    \
    _Pragma("unroll 1") for (int c = 0; c < 8; c++) {                          \
      const unsigned short* wsrc =                                             \
          (WBLOB) + (size_t)((CB) * 8 + c + 1) * 18432;                        \
      const int ch32 = (c + 1) * 32;                                           \
      const bool st = (c < 7);                                                 \
      const short8* lw8 = (const short8*)lwc;                                  \
      const short8* lx8 = (const short8*)lxc;                                  \
      CONV_PHASE(0, {                                                          \
        if (st) {                                                              \
          SG_X(0, ch32, lxn); SG_X(1, ch32, lxn);                              \
          SG_W(0, wsrc, lwn); SG_W(1, wsrc, lwn);                              \
        }                                                                      \
      })                                                                       \
      BARX();                                                                  \
      CONV_PHASE(1, {                                                          \
        if (st) {                                                              \
          SG_X(2, ch32, lxn); SG_X(3, ch32, lxn);                              \
          SG_W(2, wsrc, lwn); SG_W(3, wsrc, lwn);                              \
        }                                                                      \
      })                                                                       \
      BARX();                                                                  \
      CONV_PHASE(2, {                                                          \
        if (st) {                                                              \
          SG_X(4, ch32, lxn);                                                  \
          SG_W(4, wsrc, lwn);                                                  \
        }                                                                      \
      })                                                                       \
      VMC0();                                                                  \
      BARX();                                                                  \
      unsigned short* tp_;                                                     \
      tp_ = lwc; lwc = lwn; lwn = tp_;                                         \
      tp_ = lxc; lxc = lxn; lxn = tp_;                                         \
    }                                                                          \
  }

// ---- tower conv layer (bf16 in -> bf16 out, +bias, ReLU) ----
__global__ __launch_bounds__(512, 2) void conv_tower_mfma(
    const unsigned short* __restrict__ xin, unsigned short* __restrict__ xout,
    const unsigned short* __restrict__ wblob_cls,
    const unsigned short* __restrict__ wblob_box,
    const float* __restrict__ bias_cls, const float* __restrict__ bias_box,
    int in_n_stride, int in_tw_stride) {
  __shared__ __align__(16) unsigned short lds_w[2][18432];
  __shared__ __align__(16) unsigned short lds_x[2][20480];
  const int t = threadIdx.x, lane = t & 63, wv = t >> 6;
  const int q = lane >> 4, n16 = lane & 15;
  const int R4 = (wv >> 1) * 4, cwn = (wv & 1) * 16 + n16;
  int l, h0, w0, H, W, Wp, loff;
  decode_tile(blockIdx.x, l, h0, w0, H, W, Wp, loff);
  const int Hpad = H + 2;
  const int cb = blockIdx.y;
  const int n = blockIdx.z >> 1, tw = blockIdx.z & 1;
  const unsigned short* wblob = tw ? wblob_box : wblob_cls;
  const float* bias = tw ? bias_box : bias_cls;
  const unsigned short* inp =
      xin + ((size_t)n * in_n_stride + (size_t)tw * in_tw_stride + loff) * 256;
  unsigned short* outp = xout + ((size_t)(n * 2 + tw) * LVLTOT + loff) * 256;

  floatx4 acc[4][4];
#pragma unroll
  for (int i = 0; i < 4; i++)
#pragma unroll
    for (int jj = 0; jj < 4; jj++) acc[i][jj] = (floatx4){0.f, 0.f, 0.f, 0.f};

  CONV_MAIN_LOOP(inp, wblob, cb)

  // epilogue: +bias, relu, bf16, store 4 consecutive channels (8B) per lane
#pragma unroll
  for (int cA = 0; cA < 4; cA++) {
    floatx4 bb = *(const floatx4*)(bias + cb * 64 + cA * 16 + q * 4);
#pragma unroll
    for (int rr = 0; rr < 4; rr++) {
      int h = h0 + R4 + rr;
      int w_ = w0 + cwn;
      if (h < H && w_ < W) {
        unsigned short pk[4];
#pragma unroll
        for (int rg = 0; rg < 4; rg++)
          pk[rg] = f2bf(fmaxf(acc[cA][rr][rg] + bb[rg], 0.f));
        size_t base =
            ((size_t)(h + 1) * Wp + (w_ + 1)) * 256 + cb * 64 + cA * 16 + q * 4;
        *(unsigned long long*)(outp + base) = *(unsigned long long*)pk;
      }
    }
  }
}

// ---- merged final conv (y<12: cls cb=y; y==12: box), permuted fp32 out ----
__global__ __launch_bounds__(512, 2) void conv_final_mfma(
    const unsigned short* __restrict__ xin, float* __restrict__ out,
    const unsigned short* __restrict__ wblob_cls,
    const unsigned short* __restrict__ wblob_box,
    const float* __restrict__ bias_cls, const float* __restrict__ bias_box) {
  __shared__ __align__(16) unsigned short lds_w[2][18432];
  __shared__ __align__(16) unsigned short lds_x[2][20480];
  const int t = threadIdx.x, lane = t & 63, wv = t >> 6;
  const int q = lane >> 4, n16 = lane & 15;
  const int R4 = (wv >> 1) * 4, cwn = (wv & 1) * 16 + n16;
  int l, h0, w0, H, W, Wp, loff;
  decode_tile(blockIdx.x, l, h0, w0, H, W, Wp, loff);
  const int Hpad = H + 2;
  const int yb = blockIdx.y;
  const bool is_cls = yb < 12;
  const int cb = is_cls ? yb : 0;
  const int tw = is_cls ? 0 : 1;
  const int Cout = is_cls ? 720 : 36;
  const unsigned short* wblob = is_cls ? wblob_cls : wblob_box;
  const float* bias = is_cls ? bias_cls : bias_box;
  const int n = blockIdx.z;
  const int RB[5] = {0, 90000, 112500, 118125, 119646};
  const unsigned short* inp = xin + ((size_t)(n * 2 + tw) * LVLTOT + loff) * 256;

  floatx4 acc[4][4];
#pragma unroll
  for (int i = 0; i < 4; i++)
#pragma unroll
    for (int jj = 0; jj < 4; jj++) acc[i][jj] = (floatx4){0.f, 0.f, 0.f, 0.f};

  CONV_MAIN_LOOP(inp, wblob, cb)

#pragma unroll
  for (int cA = 0; cA < 4; cA++) {
    int co0 = cb * 64 + cA * 16 + q * 4;
    if (co0 >= Cout) continue;
    floatx4 bb = *(const floatx4*)(bias + co0);
    int a = is_cls ? (co0 / 80) : (co0 >> 2);
    int col0 = is_cls ? (co0 - a * 80) : 80;
#pragma unroll
    for (int rr = 0; rr < 4; rr++) {
      int h = h0 + R4 + rr;
      int w_ = w0 + cwn;
      if (h < H && w_ < W) {
        size_t ridx = (size_t)RB[l] + ((size_t)h * W + w_) * 9 + a;
        floatx4 v;
#pragma unroll
        for (int rg = 0; rg < 4; rg++) v[rg] = acc[cA][rr][rg] + bb[rg];
        *(floatx4*)(out + ((size_t)n * 120087 + ridx) * 84 + col0) = v;
      }
    }
  }
}

extern "C" void kernel_launch(void* const* d_in, const int* in_sizes, int n_in,
                              void* d_out, int out_size, void* d_ws,
                              size_t ws_size, hipStream_t stream) {
  // ws layout (bytes):
  //   bufB [0, 28964864)    (X0 aliased to bufB planes 2,3: dead after layer 1)
  //   X0   [14482432, 28964864)
  //   bufA [28964864, 57929728)
  //   tower blobs 8 x 1179648 at 57929728 (cls0..3, box0..3)
  //   cls final blob 3538944 at 67366912; box final blob 294912 at 70905856
  char* ws = (char*)d_ws;
  unsigned short* bufB = (unsigned short*)(ws);
  unsigned short* X0 = (unsigned short*)(ws + 14482432);
  unsigned short* bufA = (unsigned short*)(ws + 28964864);
  unsigned short* tb[8];
  for (int i = 0; i < 8; i++)
    tb[i] = (unsigned short*)(ws + 57929728 + (size_t)i * 1179648);
  unsigned short* fb_cls = (unsigned short*)(ws + 67366912);
  unsigned short* fb_box = (unsigned short*)(ws + 70905856);

  float* out = (float*)d_out;

  PrepArgs pa;
  for (int i = 0; i < 5; i++) pa.f[i] = (const float*)d_in[i];
  for (int i = 0; i < 4; i++) {
    pa.w[i] = (const float*)d_in[5 + 2 * i];       // cls_w0..3
    pa.w[4 + i] = (const float*)d_in[13 + 2 * i];  // box_w0..3
    pa.wdst[i] = tb[i];
    pa.wdst[4 + i] = tb[4 + i];
    pa.cout[i] = pa.cout[4 + i] = 256;
  }
  pa.w[8] = (const float*)d_in[21]; pa.wdst[8] = fb_cls; pa.cout[8] = 720;
  pa.w[9] = (const float*)d_in[23]; pa.wdst[9] = fb_box; pa.cout[9] = 36;
  // padded-co block counts: towers 256 each, cls 768, box 64
  int off = 0;
  for (int i = 0; i < 8; i++) { pa.wblk_off[i] = off; off += 256; }
  pa.wblk_off[8] = off; off += 768;
  pa.wblk_off[9] = off; off += 64;
  pa.wblk_off[10] = off;  // 2880
  pa.x0 = X0;
  pa.bufA = bufA;
  pa.bufB = bufB;

  prep<<<dim3(4770), 256, 0, stream>>>(pa);

  const float *cls_b[4], *box_b[4];
  for (int i = 0; i < 4; i++) {
    cls_b[i] = (const float*)d_in[6 + 2 * i];
    box_b[i] = (const float*)d_in[14 + 2 * i];
  }

  dim3 gt(40, 4, 4);
  conv_tower_mfma<<<gt, 512, 0, stream>>>(X0, bufA, tb[0], tb[4], cls_b[0],
                                          box_b[0], LVLTOT, 0);
  conv_tower_mfma<<<gt, 512, 0, stream>>>(bufA, bufB, tb[1], tb[5], cls_b[1],
                                          box_b[1], 2 * LVLTOT, LVLTOT);
  conv_tower_mfma<<<gt, 512, 0, stream>>>(bufB, bufA, tb[2], tb[6], cls_b[2],
                                          box_b[2], 2 * LVLTOT, LVLTOT);
  conv_tower_mfma<<<gt, 512, 0, stream>>>(bufA, bufB, tb[3], tb[7], cls_b[3],
                                          box_b[3], 2 * LVLTOT, LVLTOT);

  conv_final_mfma<<<dim3(40, 13, 2), 512, 0, stream>>>(
      bufB, out, fb_cls, fb_box, (const float*)d_in[22], (const float*)d_in[24]);
}